// Round 2
// 268.852 us; speedup vs baseline: 1.0017x; 1.0017x over previous
//
#include <hip/hip_runtime.h>
#include <math.h>

#define N 2048
#define BATCH 16

typedef float vfloat4 __attribute__((ext_vector_type(4)));

// ---------------------------------------------------------------------------
// Kernel 1: ndsum[b][j] = -sum_k |s[b][j] - s[b][k]|   (negated for the fma)
// grid = BATCH*16 = 256 blocks, 512 threads (8 waves/CU vs previous 2).
// Each block stages the 2048-float score row (8 KB LDS) and computes 128 j's;
// the k-range is split 4-ways across thread quarters to shorten the serial
// dependence chain 4x and fill the SIMDs; partials tree-reduced in LDS.
// ---------------------------------------------------------------------------
__global__ __launch_bounds__(512) void bsum_kernel(const float* __restrict__ scores,
                                                   float* __restrict__ ndsum) {
    __shared__ float s_sh[N];
    __shared__ float part[4][128];
    const int b = blockIdx.x >> 4;           // 16 blocks per batch
    const int jBase = (blockIdx.x & 15) * 128;
    const float* s = scores + (size_t)b * N;

    // 512 float4 over 512 threads: one vector load each
    ((float4*)s_sh)[threadIdx.x] = ((const float4*)s)[threadIdx.x];
    __syncthreads();

    const int jl = threadIdx.x & 127;        // 0..127  (j within block)
    const int q  = threadIdx.x >> 7;         // 0..3    (k-quarter)
    const float sj = s_sh[jBase + jl];
    const int k4Base = q * (N / 16);         // 128 float4 per quarter

    float acc = 0.f;
#pragma unroll 8
    for (int k4 = 0; k4 < N / 16; ++k4) {
        float4 v = ((const float4*)s_sh)[k4Base + k4];  // wave-uniform: broadcast
        acc += fabsf(sj - v.x) + fabsf(sj - v.y) + fabsf(sj - v.z) + fabsf(sj - v.w);
    }
    part[q][jl] = acc;
    __syncthreads();

    if (threadIdx.x < 128) {
        float d = part[0][threadIdx.x] + part[1][threadIdx.x] +
                  part[2][threadIdx.x] + part[3][threadIdx.x];
        ndsum[(size_t)b * N + jBase + threadIdx.x] = -d;
    }
}

// ---------------------------------------------------------------------------
// Kernel 2: P_hat[b][i][j] = softmax_j( scaling[i]*s[j] - Bsum[j] )
// Register-resident: each wave loads its 32 columns of s and -Bsum into
// 64 VGPRs ONCE (they are row-invariant; only the scalar c changes per row)
// and produces 8 consecutive rows. No LDS, no __syncthreads, loads amortized
// 8x, nontemporal stores (268 MB streaming, don't cycle L2).
// grid = BATCH * 64 = 1024 blocks of 256 threads (4 waves x 8 rows = 32
// rows/block); 4 blocks/CU -> 4 waves/SIMD at VGPR<=128.
// ---------------------------------------------------------------------------
__global__ __launch_bounds__(256, 4) void softmax_kernel(const float* __restrict__ scores,
                                                         const float* __restrict__ ndsum,
                                                         float* __restrict__ out) {
    const int b = blockIdx.x >> 6;                       // 64 blocks per batch
    const int wave = threadIdx.x >> 6;
    const int lane = threadIdx.x & 63;
    const int rowBase = (blockIdx.x & 63) * 32 + wave * 8;

    const float* s  = scores + (size_t)b * N;
    const float* nd = ndsum  + (size_t)b * N;

    float4 s4[8], nd4[8];
#pragma unroll
    for (int it = 0; it < 8; ++it) {
        const int idx = it * 64 + lane;                  // float4 index -> j = 4*idx
        s4[it]  = ((const float4*)s)[idx];
        nd4[it] = ((const float4*)nd)[idx];
    }

    float* obase = out + ((size_t)b * N + rowBase) * N;

#pragma unroll 1
    for (int r = 0; r < 8; ++r) {
        const float c = (float)(N - 1 - 2 * (rowBase + r));   // scaling[i]
        float lg[32];
        float m = -INFINITY;
#pragma unroll
        for (int it = 0; it < 8; ++it) {
            float l0 = fmaf(c, s4[it].x, nd4[it].x);
            float l1 = fmaf(c, s4[it].y, nd4[it].y);
            float l2 = fmaf(c, s4[it].z, nd4[it].z);
            float l3 = fmaf(c, s4[it].w, nd4[it].w);
            lg[it * 4 + 0] = l0;
            lg[it * 4 + 1] = l1;
            lg[it * 4 + 2] = l2;
            lg[it * 4 + 3] = l3;
            m = fmaxf(m, fmaxf(fmaxf(l0, l1), fmaxf(l2, l3)));
        }
#pragma unroll
        for (int off = 32; off > 0; off >>= 1)
            m = fmaxf(m, __shfl_xor(m, off, 64));

        float sum = 0.f;
#pragma unroll
        for (int k = 0; k < 32; ++k) {
            lg[k] = __expf(lg[k] - m);
            sum += lg[k];
        }
#pragma unroll
        for (int off = 32; off > 0; off >>= 1)
            sum += __shfl_xor(sum, off, 64);

        const float inv = __builtin_amdgcn_rcpf(sum);

        float* orow = obase + (size_t)r * N;
#pragma unroll
        for (int it = 0; it < 8; ++it) {
            vfloat4 o;
            o.x = lg[it * 4 + 0] * inv;
            o.y = lg[it * 4 + 1] * inv;
            o.z = lg[it * 4 + 2] * inv;
            o.w = lg[it * 4 + 3] * inv;
            __builtin_nontemporal_store(o, (vfloat4*)orow + (it * 64 + lane));
        }
    }
}

extern "C" void kernel_launch(void* const* d_in, const int* in_sizes, int n_in,
                              void* d_out, int out_size, void* d_ws, size_t ws_size,
                              hipStream_t stream) {
    const float* scores = (const float*)d_in[0];
    float* out = (float*)d_out;
    float* ndsum = (float*)d_ws;   // BATCH*N floats = 128 KB scratch

    bsum_kernel<<<BATCH * 16, 512, 0, stream>>>(scores, ndsum);
    softmax_kernel<<<BATCH * 64, 256, 0, stream>>>(scores, ndsum, out);
}